// Round 6
// baseline (146.809 us; speedup 1.0000x reference)
//
#include <hip/hip_runtime.h>
#include <hip/hip_fp16.h>
#include <stdint.h>

typedef _Float16 f16;
typedef __attribute__((ext_vector_type(8))) _Float16 f16x8;
typedef __attribute__((ext_vector_type(4))) _Float16 f16x4;
typedef __attribute__((ext_vector_type(4))) float f32x4;

#define SEQ 2048
#define DIM 1024
#define NBATCH 2
#define MTOT 4096  // NBATCH*SEQ

__global__ void fill_kernel(float* p, float v, int n){
  int i = blockIdx.x * 256 + threadIdx.x;
  if (i < n) p[i] = v;
}

// Merged fp32->fp16 convert + rowacc zero-init.
// blocks 0..4095 -> x, 4096..8191 -> weights, 8192 -> zero rowacc.
__global__ void cvt_all(const float* __restrict__ x, const float* __restrict__ Wq,
                        const float* __restrict__ Wk, const float* __restrict__ Wv,
                        const float* __restrict__ Wo,
                        f16* __restrict__ x16, f16* __restrict__ Wcat, f16* __restrict__ Wo16,
                        float* __restrict__ rowacc){
  int b = blockIdx.x;
  if (b == 8192){
    float4 z = {0.f, 0.f, 0.f, 0.f};
#pragma unroll
    for (int i = 0; i < 4; i++) ((float4*)rowacc)[threadIdx.x + i * 256] = z;
    return;
  }
  const float* src; f16* dst; int i;
  if (b < 4096){
    src = x; dst = x16; i = b * 256 + threadIdx.x;
  } else {
    int t = (b - 4096) >> 10;
    i = ((b - 4096) & 1023) * 256 + threadIdx.x;
    src = t == 0 ? Wq : t == 1 ? Wk : t == 2 ? Wv : Wo;
    dst = (t == 3) ? Wo16 : Wcat + (size_t)t * DIM * DIM;
  }
  float4 v = ((const float4*)src)[i];
  ((f16x4*)dst)[i] = (f16x4){(f16)v.x, (f16)v.y, (f16)v.z, (f16)v.w};
}

#define GLOAD16(SRC, DST) __builtin_amdgcn_global_load_lds( \
    (__attribute__((address_space(1))) void*)(SRC), \
    (__attribute__((address_space(3))) void*)(DST), 16, 0, 0)

// ---------------------------------------------------------------------------
// 128x128 GEMM, BK=32, TRIPLE-buffered LDS (3 x 16 KiB = 48 KiB -> 3 blocks/CU),
// depth-2 counted-vmcnt pipeline (T4): stage tile t+2 during tile t; before
// consuming tile t wait vmcnt(4) (leave tile t+1's 4 per-wave loads in flight;
// vmcnt(0) on last iter). Per-wave FIFO proof: loads newer than tile t at the
// wait point = exactly tile t+1's 4 (t+2 issued after). Each wave counts its
// own loads; raw s_barrier makes tile-t visibility workgroup-wide.
// LDS tile layout: logical 128x32 folded to [64 rows][64 f16] (row stride
// 128 B = all 32 banks): chunk(row64, cb'), cb' = cb ^ (row64&7),
// cb = rowgrp*4 + k/8, rowgrp = logical_row>>6. Frag reads land 2-way max (free).
// C = A @ B^T. MODEs:
//   3: f16 transposed out -> Ct[bz][col][row] (vWo^T)
//   4: fused qkv: col<2048 -> Ch(q|k cat, ldc), col>=2048 -> v[row][col-2048]
//   5: P = exp(min(theta-10,11)) f16 -> Ch; fused row-sum atomicAdd -> rowacc
//   6: fp32 out = acc/rowacc[row] + bias0[col] -> Cf   (final)
// ---------------------------------------------------------------------------
template<int MODE>
__global__ __launch_bounds__(256, 3)
void gemm_p3(const f16* __restrict__ A, const f16* __restrict__ B,
             int K, int lda, int ldb, long bsA, long bsB, long bsC,
             float* __restrict__ Cf, f16* __restrict__ Ch, f16* __restrict__ Ct,
             const float* __restrict__ bias0, const float* __restrict__ bias1,
             const float* __restrict__ bias2, float* __restrict__ rowacc,
             int ldc)
{
  __shared__ __align__(16) f16 As[3][4096];   // 3 bufs x (64 x 64 f16) = logical 128x32
  __shared__ __align__(16) f16 Bs[3][4096];
  const int tid  = threadIdx.x;
  const int lane = tid & 63;
  const int wid  = tid >> 6;
  const int bm = blockIdx.x, bn = blockIdx.y, bz = blockIdx.z;

  // ---- staging map: per thread 2 chunks per operand; chunk C = l*256+tid
  // row64 = C>>3, cb' = tid&7, cb = cb' ^ (row64&7), grow = row64 + 64*(cb>>2),
  // gk = (cb&3)*8. Dest = linear chunk C (wave-uniform base + lane*16B).
  long aoff[2], boff[2];
#pragma unroll
  for (int l = 0; l < 2; l++){
    const int r64 = (l * 256 + tid) >> 3;
    const int cb  = (tid & 7) ^ (r64 & 7);
    const int grow = r64 + 64 * (cb >> 2);
    const int gk   = (cb & 3) * 8;
    aoff[l] = (long)(bm * 128 + grow) * lda + gk;
    boff[l] = (long)(bn * 128 + grow) * ldb + gk;
  }
  const f16* Ag = A + (long)bz * bsA;
  const f16* Bg = B + (long)bz * bsB;

#define STG(E, T) do{ \
    GLOAD16(Ag + aoff[0] + (long)(T)*32, &As[E][       tid*8]); \
    GLOAD16(Ag + aoff[1] + (long)(T)*32, &As[E][2048 + tid*8]); \
    GLOAD16(Bg + boff[0] + (long)(T)*32, &Bs[E][       tid*8]); \
    GLOAD16(Bg + boff[1] + (long)(T)*32, &Bs[E][2048 + tid*8]); \
  }while(0)

  // ---- frag-read addressing: frag i rows = wrow+i*16+l15 -> row64 = i*16+l15
  // (wrow in {0,64}), rowgrp = wrow>>6; addr = row64*64 + ((rg*4+lhi)^(l15&7))*8
  const int l15 = lane & 15, lhi = lane >> 4;
  const int wrow = (wid >> 1) * 64;
  const int wcol = (wid & 1) * 64;
  const int rga = wrow >> 6, rgb = wcol >> 6;
  int aadr[4], badr[4];
#pragma unroll
  for (int i = 0; i < 4; i++){
    aadr[i] = (i * 16 + l15) * 64 + (((rga * 4 + lhi) ^ (l15 & 7)) * 8);
    badr[i] = (i * 16 + l15) * 64 + (((rgb * 4 + lhi) ^ (l15 & 7)) * 8);
  }

  f32x4 acc[4][4] = {};
  const int NT = K >> 5;

  STG(0, 0);
  STG(1, 1);
  int d = 0, e = 2;

  for (int t = 0; t < NT; ++t){
    if (t + 1 < NT) asm volatile("s_waitcnt vmcnt(4)" ::: "memory");
    else            asm volatile("s_waitcnt vmcnt(0)" ::: "memory");
    __builtin_amdgcn_s_barrier();
    if (t + 2 < NT) STG(e, t + 2);
    f16x8 af[4], bf[4];
#pragma unroll
    for (int i = 0; i < 4; i++) af[i] = *(const f16x8*)&As[d][aadr[i]];
#pragma unroll
    for (int j = 0; j < 4; j++) bf[j] = *(const f16x8*)&Bs[d][badr[j]];
#pragma unroll
    for (int i = 0; i < 4; i++)
#pragma unroll
      for (int j = 0; j < 4; j++)
        acc[i][j] = __builtin_amdgcn_mfma_f32_16x16x32_f16(af[i], bf[j], acc[i][j], 0, 0, 0);
    d = (d == 2) ? 0 : d + 1;
    e = (e == 2) ? 0 : e + 1;
  }
#undef STG

  // Epilogue. C/D layout: col = lane&15 (cc), row = (lane>>4)*4 + reg
  const int cc = l15;
  const int rr = lhi * 4;

  if constexpr (MODE == 3){
#pragma unroll
    for (int i = 0; i < 4; i++)
#pragma unroll
      for (int j = 0; j < 4; j++){
        const int col = bn * 128 + wcol + j * 16 + cc;
        const int row0 = bm * 128 + wrow + i * 16 + rr;
        f16x4 pk = {(f16)acc[i][j][0], (f16)acc[i][j][1],
                    (f16)acc[i][j][2], (f16)acc[i][j][3]};
        *(f16x4*)&Ct[(long)bz * DIM * SEQ + (long)col * SEQ + row0] = pk;
      }
  } else if constexpr (MODE == 4){
#pragma unroll
    for (int i = 0; i < 4; i++)
#pragma unroll
      for (int j = 0; j < 4; j++){
        const int col = bn * 128 + wcol + j * 16 + cc;
        if (col < 2048){
          const float badd = (col < 1024) ? bias0[col] : bias1[col - 1024];
#pragma unroll
          for (int r = 0; r < 4; r++){
            const int row = bm * 128 + wrow + i * 16 + rr + r;
            Ch[(long)row * ldc + col] = (f16)(acc[i][j][r] + badd);
          }
        } else {
          const int dcol = col - 2048;
          const float badd = bias2[dcol];
#pragma unroll
          for (int r = 0; r < 4; r++){
            const int row = bm * 128 + wrow + i * 16 + rr + r;
            Ct[(long)row * DIM + dcol] = (f16)(acc[i][j][r] + badd);
          }
        }
      }
  } else if constexpr (MODE == 5){  // theta + unnormalized exp, fused row-sum
#pragma unroll
    for (int i = 0; i < 4; i++)
#pragma unroll
      for (int r = 0; r < 4; r++){
        const int row = bm * 128 + wrow + i * 16 + rr + r;
        float rs = 0.f;
#pragma unroll
        for (int j = 0; j < 4; j++){
          const int col = bn * 128 + wcol + j * 16 + cc;
          const float v = acc[i][j][r];
          const float e1 = __expf(-v);          // x->-inf: e1=inf -> sg=0, th=-1
          const float sg = 1.f / (1.f + e1);
          const float e2 = e1 * e1;             // e^{-2x}
          const float th = 2.f / (1.f + e2) - 1.f;
          const float theta = 0.5f + 0.2f * sg + 0.15f * th + 0.1f * fmaxf(v, 0.f);
          const float P = __expf(fminf(theta - 10.f, 11.f));
          Ch[(long)bz * bsC + (long)row * ldc + col] = (f16)P;
          rs += P;
        }
        rs += __shfl_xor(rs, 1, 64);
        rs += __shfl_xor(rs, 2, 64);
        rs += __shfl_xor(rs, 4, 64);
        rs += __shfl_xor(rs, 8, 64);
        if (cc == 0) atomicAdd(&rowacc[bz * SEQ + row], rs);
      }
  } else {  // MODE 6: final fp32 out = acc/rowsum + bias
#pragma unroll
    for (int i = 0; i < 4; i++)
#pragma unroll
      for (int r = 0; r < 4; r++){
        const int row = bm * 128 + wrow + i * 16 + rr + r;
        const float inv = 1.f / rowacc[bz * SEQ + row];
#pragma unroll
        for (int j = 0; j < 4; j++){
          const int col = bn * 128 + wcol + j * 16 + cc;
          Cf[(long)bz * bsC + (long)row * ldc + col] = acc[i][j][r] * inv + bias0[col];
        }
      }
  }
}

extern "C" void kernel_launch(void* const* d_in, const int* in_sizes, int n_in,
                              void* d_out, int out_size, void* d_ws, size_t ws_size,
                              hipStream_t stream){
  const float* x  = (const float*)d_in[0];
  const float* Wq = (const float*)d_in[1];
  const float* bq = (const float*)d_in[2];
  const float* Wk = (const float*)d_in[3];
  const float* bk = (const float*)d_in[4];
  const float* Wv = (const float*)d_in[5];
  const float* bv = (const float*)d_in[6];
  const float* Wo = (const float*)d_in[7];
  const float* bo = (const float*)d_in[8];
  float* out = (float*)d_out;

  char* ws = (char*)d_ws;
  size_t off = 0;
  auto alloc = [&](size_t bytes) -> char* {
    char* p = ws + off; off += (bytes + 255) & ~(size_t)255; return p;
  };

  f16* x16     = (f16*)alloc(2ull * MTOT * DIM);          // 8 MB
  f16* Wcat    = (f16*)alloc(2ull * 3 * DIM * DIM);       // 6 MB  [Wq;Wk;Wv]
  f16* Wo16    = (f16*)alloc(2ull * DIM * DIM);           // 2 MB
  f16* qkcat   = (f16*)alloc(2ull * MTOT * 2 * DIM);      // 16 MB [q|k] per row
  f16* vbuf    = (f16*)alloc(2ull * MTOT * DIM);          // 8 MB  v row-major
  f16* Pbuf    = (f16*)alloc(2ull * NBATCH * SEQ * SEQ);  // 16 MB unnormalized exp
  f16* vWoT    = (f16*)alloc(2ull * NBATCH * DIM * SEQ);  // 8 MB  (v@Wo^T)^T [b][e][t]
  float* rowac = (float*)alloc(4ull * MTOT);              // 16 KB row sums

  if (off > ws_size){
    fill_kernel<<<(out_size + 255) / 256, 256, 0, stream>>>(out, 12345.0f, out_size);
    return;
  }

  cvt_all<<<8193, 256, 0, stream>>>(x, Wq, Wk, Wv, Wo, x16, Wcat, Wo16, rowac);

  // fused [q|k|v] = x @ [Wq;Wk;Wv]^T + bias   (grid 32x24 = 768 blocks, NT=32)
  gemm_p3<4><<<dim3(MTOT / 128, 3 * DIM / 128, 1), 256, 0, stream>>>(
      x16, Wcat, DIM, DIM, DIM, 0, 0, 0,
      nullptr, qkcat, vbuf, bq, bk, bv, nullptr, 2 * DIM);

  // P = exp(theta(q@k^T) - 10) f16 + fused row sums  (grid 16x16x2 = 512, NT=32)
  gemm_p3<5><<<dim3(SEQ / 128, SEQ / 128, NBATCH), 256, 0, stream>>>(
      qkcat, qkcat + DIM, DIM, 2 * DIM, 2 * DIM,
      (long)SEQ * 2 * DIM, (long)SEQ * 2 * DIM, (long)SEQ * SEQ,
      nullptr, Pbuf, nullptr, nullptr, nullptr, nullptr, rowac, SEQ);

  // vWo^T = (v @ Wo^T)^T per batch  (grid 16x8x2 = 256, NT=32)
  gemm_p3<3><<<dim3(SEQ / 128, DIM / 128, NBATCH), 256, 0, stream>>>(
      vbuf, Wo16, DIM, DIM, DIM,
      (long)SEQ * DIM, 0, 0,
      nullptr, nullptr, vWoT, nullptr, nullptr, nullptr, nullptr, 0);

  // out = (P @ vWo) / rowsum + bo, fp32 to d_out  (grid 16x8x2 = 256, NT=64)
  gemm_p3<6><<<dim3(SEQ / 128, DIM / 128, NBATCH), 256, 0, stream>>>(
      Pbuf, vWoT, SEQ, SEQ, SEQ,
      (long)SEQ * SEQ, (long)DIM * SEQ, (long)SEQ * DIM,
      out, nullptr, nullptr, bo, nullptr, nullptr, rowac, DIM);
}

// Round 7
// 119.451 us; speedup vs baseline: 1.2290x; 1.2290x over previous
//
#include <hip/hip_runtime.h>
#include <hip/hip_fp16.h>
#include <stdint.h>

typedef _Float16 f16;
typedef __attribute__((ext_vector_type(8))) _Float16 f16x8;
typedef __attribute__((ext_vector_type(4))) _Float16 f16x4;
typedef __attribute__((ext_vector_type(4))) float f32x4;

#define SEQ 2048
#define DIM 1024
#define NBATCH 2
#define MTOT 4096  // NBATCH*SEQ

__global__ void fill_kernel(float* p, float v, int n){
  int i = blockIdx.x * 256 + threadIdx.x;
  if (i < n) p[i] = v;
}

// Merged fp32->fp16 convert + rowacc zero-init.
// blocks 0..4095 -> x, 4096..8191 -> weights, 8192 -> zero rowacc.
__global__ void cvt_all(const float* __restrict__ x, const float* __restrict__ Wq,
                        const float* __restrict__ Wk, const float* __restrict__ Wv,
                        const float* __restrict__ Wo,
                        f16* __restrict__ x16, f16* __restrict__ Wcat, f16* __restrict__ Wo16,
                        float* __restrict__ rowacc){
  int b = blockIdx.x;
  if (b == 8192){
    float4 z = {0.f, 0.f, 0.f, 0.f};
#pragma unroll
    for (int i = 0; i < 4; i++) ((float4*)rowacc)[threadIdx.x + i * 256] = z;
    return;
  }
  const float* src; f16* dst; int i;
  if (b < 4096){
    src = x; dst = x16; i = b * 256 + threadIdx.x;
  } else {
    int t = (b - 4096) >> 10;
    i = ((b - 4096) & 1023) * 256 + threadIdx.x;
    src = t == 0 ? Wq : t == 1 ? Wk : t == 2 ? Wv : Wo;
    dst = (t == 3) ? Wo16 : Wcat + (size_t)t * DIM * DIM;
  }
  float4 v = ((const float4*)src)[i];
  ((f16x4*)dst)[i] = (f16x4){(f16)v.x, (f16)v.y, (f16)v.z, (f16)v.w};
}

#define GLOAD16(SRC, DST) __builtin_amdgcn_global_load_lds( \
    (__attribute__((address_space(1))) void*)(SRC), \
    (__attribute__((address_space(3))) void*)(DST), 16, 0, 0)

// theta -> unnormalized exp (shift 10, clamp 11). x->-inf: e1=inf -> sg=0, th=-1.
__device__ __forceinline__ float theta_exp(float v){
  const float e1 = __expf(-v);
  const float sg = 1.f / (1.f + e1);
  const float e2 = e1 * e1;             // e^{-2x}
  const float th = 2.f / (1.f + e2) - 1.f;
  const float theta = 0.5f + 0.2f * sg + 0.15f * th + 0.1f * fmaxf(v, 0.f);
  return __expf(fminf(theta - 10.f, 11.f));
}

// ---------------------------------------------------------------------------
// 256-thread 128x128 GEMM, BK=64, single-buffered LDS (32 KiB), 2 barriers per
// K-tile (R5 structure, best measured). XOR swizzle (verified 0 conflicts):
// LDS[r][cb] = G[r][cb ^ (r&7)]; linear gload_lds dest + pre-swizzled source.
// NT = 16 (K=1024) for both modes.
// MODE 4 (qkv):  grid (32,24). A=x16, B=Wcat. col<2048 -> qkcat(+bq/bk),
//                col>=2048 -> vbuf row-major (+bv).
// MODE 7 (merged qk+vWo): grid 768 linear.
//   block < 512:  qk. A=q rows (qkcat), B=k rows (qkcat+DIM), ld 2048.
//                 epilogue: P=theta_exp -> Pbuf; rowsum atomicAdd -> rowacc.
//   block >= 512: vWo. A=vbuf rows, B=Wo16, ld 1024.
//                 epilogue: transposed f16 out -> vWoT[b][e][t].
// ---------------------------------------------------------------------------
template<int MODE>
__global__ __launch_bounds__(256, 3)
void gemm256(const f16* __restrict__ A0, const f16* __restrict__ A1,
             const f16* __restrict__ B0,
             f16* __restrict__ O0, f16* __restrict__ O1,
             const float* __restrict__ c0, const float* __restrict__ c1,
             const float* __restrict__ c2, float* __restrict__ rowacc)
{
  __shared__ __align__(16) f16 As[8192];   // 128 x 64 f16
  __shared__ __align__(16) f16 Bs[8192];
  const int tid  = threadIdx.x;
  const int lane = tid & 63;
  const int wid  = tid >> 6;

  int bm, bn, bz = 0, lda, ldb;
  const f16 *Ag, *Bg;
  bool isQK = true;
  if constexpr (MODE == 4){
    bm = blockIdx.x; bn = blockIdx.y; lda = DIM; ldb = DIM;
    Ag = A0; Bg = B0;                       // x16, Wcat
  } else {
    const int r = blockIdx.x;
    if (r < 512){                           // qk
      bz = r >> 8; const int q = r & 255; bm = q & 15; bn = q >> 4;
      Ag = A0 + (long)bz * SEQ * 2048;          // q rows
      Bg = A0 + DIM + (long)bz * SEQ * 2048;    // k rows
      lda = 2048; ldb = 2048;
    } else {                                // vWo
      isQK = false;
      int q = r - 512; bz = q >> 7; q &= 127; bm = q & 15; bn = q >> 4;
      Ag = A1 + (long)bz * SEQ * DIM;           // v rows
      Bg = B0;                                  // Wo16
      lda = DIM; ldb = DIM;
    }
  }

  // staging: load l covers row l*32+(tid>>3); dest linear; source col pre-swizzled
  const int s_r  = tid >> 3;            // 0..31
  const int s_cb = (tid & 7) ^ (s_r & 7);
  const f16* Ab = Ag + (long)(bm * 128 + s_r) * lda + s_cb * 8;
  const f16* Bb = Bg + (long)(bn * 128 + s_r) * ldb + s_cb * 8;

  // frag-read addressing (swizzled)
  const int l15 = lane & 15, l7 = lane & 7, lhi = lane >> 4;
  const int wrow = (wid >> 1) * 64;
  const int wcol = (wid & 1) * 64;
  const int ar = (wrow + l15) * 64;
  const int br = (wcol + l15) * 64;
  const int cb0 = ((0 + lhi) ^ l7) * 8;
  const int cb1 = ((4 + lhi) ^ l7) * 8;

  f32x4 acc[4][4] = {};

  for (int t = 0; t < 16; ++t){
    __syncthreads();                     // prev tile's ds_reads done
    GLOAD16(Ab + (long)t*64,                  &As[       tid*8]);
    GLOAD16(Ab + (long)t*64 + (long)32 * lda, &As[2048 + tid*8]);
    GLOAD16(Ab + (long)t*64 + (long)64 * lda, &As[4096 + tid*8]);
    GLOAD16(Ab + (long)t*64 + (long)96 * lda, &As[6144 + tid*8]);
    GLOAD16(Bb + (long)t*64,                  &Bs[       tid*8]);
    GLOAD16(Bb + (long)t*64 + (long)32 * ldb, &Bs[2048 + tid*8]);
    GLOAD16(Bb + (long)t*64 + (long)64 * ldb, &Bs[4096 + tid*8]);
    GLOAD16(Bb + (long)t*64 + (long)96 * ldb, &Bs[6144 + tid*8]);
    __syncthreads();                     // staging landed (vmcnt drained)
    f16x8 af[4], bf[4];
#pragma unroll
    for (int i = 0; i < 4; i++) af[i] = *(const f16x8*)&As[ar + i * 1024 + cb0];
#pragma unroll
    for (int j = 0; j < 4; j++) bf[j] = *(const f16x8*)&Bs[br + j * 1024 + cb0];
#pragma unroll
    for (int i = 0; i < 4; i++)
#pragma unroll
      for (int j = 0; j < 4; j++)
        acc[i][j] = __builtin_amdgcn_mfma_f32_16x16x32_f16(af[i], bf[j], acc[i][j], 0, 0, 0);
#pragma unroll
    for (int i = 0; i < 4; i++) af[i] = *(const f16x8*)&As[ar + i * 1024 + cb1];
#pragma unroll
    for (int j = 0; j < 4; j++) bf[j] = *(const f16x8*)&Bs[br + j * 1024 + cb1];
#pragma unroll
    for (int i = 0; i < 4; i++)
#pragma unroll
      for (int j = 0; j < 4; j++)
        acc[i][j] = __builtin_amdgcn_mfma_f32_16x16x32_f16(af[i], bf[j], acc[i][j], 0, 0, 0);
  }

  // Epilogue. C/D layout: col = lane&15 (cc), row = (lane>>4)*4 + reg
  const int cc = l15;
  const int rr = lhi * 4;

  if constexpr (MODE == 4){
#pragma unroll
    for (int i = 0; i < 4; i++)
#pragma unroll
      for (int j = 0; j < 4; j++){
        const int col = bn * 128 + wcol + j * 16 + cc;
        if (col < 2048){
          const float badd = (col < 1024) ? c0[col] : c1[col - 1024];
#pragma unroll
          for (int r = 0; r < 4; r++){
            const int row = bm * 128 + wrow + i * 16 + rr + r;
            O0[(long)row * 2048 + col] = (f16)(acc[i][j][r] + badd);
          }
        } else {
          const int dcol = col - 2048;
          const float badd = c2[dcol];
#pragma unroll
          for (int r = 0; r < 4; r++){
            const int row = bm * 128 + wrow + i * 16 + rr + r;
            O1[(long)row * DIM + dcol] = (f16)(acc[i][j][r] + badd);
          }
        }
      }
  } else {
    if (isQK){   // P = theta_exp, fused row-sum
#pragma unroll
      for (int i = 0; i < 4; i++)
#pragma unroll
        for (int r = 0; r < 4; r++){
          const int row = bm * 128 + wrow + i * 16 + rr + r;
          float rs = 0.f;
#pragma unroll
          for (int j = 0; j < 4; j++){
            const int col = bn * 128 + wcol + j * 16 + cc;
            const float P = theta_exp(acc[i][j][r]);
            O0[(long)bz * SEQ * SEQ + (long)row * SEQ + col] = (f16)P;
            rs += P;
          }
          rs += __shfl_xor(rs, 1, 64);
          rs += __shfl_xor(rs, 2, 64);
          rs += __shfl_xor(rs, 4, 64);
          rs += __shfl_xor(rs, 8, 64);
          if (cc == 0) atomicAdd(&rowacc[bz * SEQ + row], rs);
        }
    } else {     // vWoT[b][e][t] transposed store
#pragma unroll
      for (int i = 0; i < 4; i++)
#pragma unroll
        for (int j = 0; j < 4; j++){
          const int col = bn * 128 + wcol + j * 16 + cc;
          const int row0 = bm * 128 + wrow + i * 16 + rr;
          f16x4 pk = {(f16)acc[i][j][0], (f16)acc[i][j][1],
                      (f16)acc[i][j][2], (f16)acc[i][j][3]};
          *(f16x4*)&O1[(long)bz * DIM * SEQ + (long)col * SEQ + row0] = pk;
        }
    }
  }
}

// ---------------------------------------------------------------------------
// 512-thread 128x128 GEMM for the final out = (P @ vWo)/rowsum + bo.
// 8 waves (2m x 4n, per-wave 64x32) -> 2 waves/SIMD at 1 block/CU (grid 256).
// Same single-buffer BK=64 loop; 4 gloads/thread. K=2048 -> NT=32.
// A = Pbuf (lda 2048), B = vWoT (ldb 2048), fp32 out.
// ---------------------------------------------------------------------------
__global__ __launch_bounds__(512, 2)
void gemm512_final(const f16* __restrict__ Pb, const f16* __restrict__ Vw,
                   float* __restrict__ out, const float* __restrict__ bo,
                   const float* __restrict__ rowacc)
{
  __shared__ __align__(16) f16 As[8192];   // 128 x 64
  __shared__ __align__(16) f16 Bs[8192];
  const int tid  = threadIdx.x;
  const int lane = tid & 63;
  const int wid  = tid >> 6;
  const int bm = blockIdx.x, bn = blockIdx.y, bz = blockIdx.z;

  const f16* Ag = Pb + (long)bz * SEQ * SEQ;
  const f16* Bg = Vw + (long)bz * DIM * SEQ;

  // staging: thread covers rows (tid>>3) and (tid>>3)+64, swizzled colblk
  const int s_r  = tid >> 3;            // 0..63
  const int s_cb = (tid & 7) ^ (s_r & 7);
  const f16* Ab = Ag + (long)(bm * 128 + s_r) * SEQ + s_cb * 8;
  const f16* Bb = Bg + (long)(bn * 128 + s_r) * SEQ + s_cb * 8;

  // frag-read addressing: wave grid 2m x 4n, per-wave 64 rows x 32 cols
  const int l15 = lane & 15, l7 = lane & 7, lhi = lane >> 4;
  const int wrow = (wid >> 2) * 64;
  const int wcol = (wid & 3) * 32;
  const int ar = (wrow + l15) * 64;
  const int br = (wcol + l15) * 64;
  const int cb0 = ((0 + lhi) ^ l7) * 8;
  const int cb1 = ((4 + lhi) ^ l7) * 8;

  f32x4 acc[4][2] = {};

  for (int t = 0; t < 32; ++t){
    __syncthreads();
    GLOAD16(Ab + (long)t*64,                  &As[       tid*8]);
    GLOAD16(Ab + (long)t*64 + (long)64 * SEQ, &As[4096 + tid*8]);
    GLOAD16(Bb + (long)t*64,                  &Bs[       tid*8]);
    GLOAD16(Bb + (long)t*64 + (long)64 * SEQ, &Bs[4096 + tid*8]);
    __syncthreads();
    f16x8 af[4], bf[2];
#pragma unroll
    for (int i = 0; i < 4; i++) af[i] = *(const f16x8*)&As[ar + i * 1024 + cb0];
#pragma unroll
    for (int j = 0; j < 2; j++) bf[j] = *(const f16x8*)&Bs[br + j * 1024 + cb0];
#pragma unroll
    for (int i = 0; i < 4; i++)
#pragma unroll
      for (int j = 0; j < 2; j++)
        acc[i][j] = __builtin_amdgcn_mfma_f32_16x16x32_f16(af[i], bf[j], acc[i][j], 0, 0, 0);
#pragma unroll
    for (int i = 0; i < 4; i++) af[i] = *(const f16x8*)&As[ar + i * 1024 + cb1];
#pragma unroll
    for (int j = 0; j < 2; j++) bf[j] = *(const f16x8*)&Bs[br + j * 1024 + cb1];
#pragma unroll
    for (int i = 0; i < 4; i++)
#pragma unroll
      for (int j = 0; j < 2; j++)
        acc[i][j] = __builtin_amdgcn_mfma_f32_16x16x32_f16(af[i], bf[j], acc[i][j], 0, 0, 0);
  }

  const int cc = l15;
  const int rr = lhi * 4;
#pragma unroll
  for (int i = 0; i < 4; i++)
#pragma unroll
    for (int r = 0; r < 4; r++){
      const int row = bm * 128 + wrow + i * 16 + rr + r;
      const float inv = 1.f / rowacc[bz * SEQ + row];
#pragma unroll
      for (int j = 0; j < 2; j++){
        const int col = bn * 128 + wcol + j * 16 + cc;
        out[(long)bz * SEQ * DIM + (long)row * DIM + col] = acc[i][j][r] * inv + bo[col];
      }
    }
}

extern "C" void kernel_launch(void* const* d_in, const int* in_sizes, int n_in,
                              void* d_out, int out_size, void* d_ws, size_t ws_size,
                              hipStream_t stream){
  const float* x  = (const float*)d_in[0];
  const float* Wq = (const float*)d_in[1];
  const float* bq = (const float*)d_in[2];
  const float* Wk = (const float*)d_in[3];
  const float* bk = (const float*)d_in[4];
  const float* Wv = (const float*)d_in[5];
  const float* bv = (const float*)d_in[6];
  const float* Wo = (const float*)d_in[7];
  const float* bo = (const float*)d_in[8];
  float* out = (float*)d_out;

  char* ws = (char*)d_ws;
  size_t off = 0;
  auto alloc = [&](size_t bytes) -> char* {
    char* p = ws + off; off += (bytes + 255) & ~(size_t)255; return p;
  };

  f16* x16     = (f16*)alloc(2ull * MTOT * DIM);          // 8 MB
  f16* Wcat    = (f16*)alloc(2ull * 3 * DIM * DIM);       // 6 MB  [Wq;Wk;Wv]
  f16* Wo16    = (f16*)alloc(2ull * DIM * DIM);           // 2 MB
  f16* qkcat   = (f16*)alloc(2ull * MTOT * 2 * DIM);      // 16 MB [q|k] per row
  f16* vbuf    = (f16*)alloc(2ull * MTOT * DIM);          // 8 MB  v row-major
  f16* Pbuf    = (f16*)alloc(2ull * NBATCH * SEQ * SEQ);  // 16 MB unnormalized exp
  f16* vWoT    = (f16*)alloc(2ull * NBATCH * DIM * SEQ);  // 8 MB  (v@Wo^T)^T [b][e][t]
  float* rowac = (float*)alloc(4ull * MTOT);              // 16 KB row sums

  if (off > ws_size){
    fill_kernel<<<(out_size + 255) / 256, 256, 0, stream>>>(out, 12345.0f, out_size);
    return;
  }

  cvt_all<<<8193, 256, 0, stream>>>(x, Wq, Wk, Wv, Wo, x16, Wcat, Wo16, rowac);

  // fused [q|k|v] = x @ [Wq;Wk;Wv]^T + bias   (grid 32x24 = 768 blocks, 3/CU)
  gemm256<4><<<dim3(MTOT / 128, 3 * DIM / 128, 1), 256, 0, stream>>>(
      x16, nullptr, Wcat, qkcat, vbuf, bq, bk, bv, nullptr);

  // merged: qk->P(+rowsum)  [blocks 0..511]  and  vWo^T  [blocks 512..767]
  gemm256<7><<<768, 256, 0, stream>>>(
      qkcat, vbuf, Wo16, Pbuf, vWoT, nullptr, nullptr, nullptr, rowac);

  // out = (P @ vWo)/rowsum + bo  (grid 16x8x2 = 256 blocks, 8 waves each)
  gemm512_final<<<dim3(SEQ / 128, DIM / 128, NBATCH), 512, 0, stream>>>(
      Pbuf, vWoT, out, bo, rowac);
}